// Round 7
// baseline (305.385 us; speedup 1.0000x reference)
//
#include <hip/hip_runtime.h>
#include <math.h>

// Problem constants
#define NB   4
#define SEQ  1024
#define DMOD 512
#define NHD  8
#define DK   64

typedef unsigned short ushort_t;
typedef __attribute__((ext_vector_type(8))) short bf16x8;
typedef __attribute__((ext_vector_type(4))) float f32x4;

// ---------------- workspace layout (bytes) ----------------
#define XQ_OFF   1024
#define XK_OFF   (XQ_OFF + 4194304)
#define XV_OFF   (XK_OFF + 4194304)
#define WQ_OFF   (XV_OFF + 4194304)
#define WK_OFF   (WQ_OFF + 524288)
#define WV_OFF   (WK_OFF + 524288)
#define WF_OFF   (WV_OFF + 524288)
#define QBF_OFF  (WF_OFF + 524288)
#define KBF_OFF  (QBF_OFF + 4194304)
#define VT_OFF   (KBF_OFF + 12582912)
// aliases (stream-ordered safe):
#define POSBF_OFF XQ_OFF  // 4MB packed-bf16 pos; written by setup (XQ region unused
                          // now that qkv reads fp32 directly), read by fused_attn,
                          // overwritten by O2 afterwards.
#define O2_OFF   XQ_OFF   // fp32 8MB, written by fc AFTER fused_attn
#define OBF_OFF  XV_OFF   // bf16 4MB, written by fused_attn

__device__ inline ushort_t f2bf(float x) {
    unsigned u = __builtin_bit_cast(unsigned, x);
    unsigned r = (u + 0x7FFFu + ((u >> 16) & 1u)) >> 16;
    return (ushort_t)r;
}
__device__ inline unsigned pk2(float a, float b) {
    return (unsigned)f2bf(a) | ((unsigned)f2bf(b) << 16);
}

// ---------------------------------------------------------------------------
// Merged setup kernel (R6): poscvt (blocks 0..1023) + weight cvt (1024..2047)
// + parallelized prep (block 2048). Was 3 dispatches + a serial 1-block prep.
// ---------------------------------------------------------------------------
__global__ __launch_bounds__(256)
void setup_kernel(const float* __restrict__ pos,
                  const float* __restrict__ w_qs, const float* __restrict__ w_ks,
                  const float* __restrict__ w_vs, const float* __restrict__ w_fc,
                  const float* __restrict__ rp_w1, const float* __restrict__ rp_b1,
                  const float* __restrict__ rp_w2, const float* __restrict__ rp_b2,
                  unsigned* __restrict__ posbf,
                  ushort_t* __restrict__ WQ, ushort_t* __restrict__ WK,
                  ushort_t* __restrict__ WV, ushort_t* __restrict__ WF,
                  float* __restrict__ ws)
{
    const int bid = blockIdx.x;
    const int tid = threadIdx.x;
    if (bid < 1024) {                       // pos -> packed bf16 pairs
        int t = bid * 256 + tid;
        float4 a = *(const float4*)&pos[t * 8];
        float4 b = *(const float4*)&pos[t * 8 + 4];
        uint4 o = {pk2(a.x, a.y), pk2(a.z, a.w), pk2(b.x, b.y), pk2(b.z, b.w)};
        *(uint4*)&posbf[t * 4] = o;
    } else if (bid < 2048) {                // 4 weight matrices -> bf16
        int which = (bid - 1024) >> 8;
        int t = ((bid - 1024) & 255) * 256 + tid;
        const float* s = (which == 0) ? w_qs : (which == 1) ? w_ks
                       : (which == 2) ? w_vs : w_fc;
        ushort_t* d = (which == 0) ? WQ : (which == 1) ? WK
                    : (which == 2) ? WV : WF;
        float4 v = *(const float4*)&s[t * 4];
        uint2 o = {pk2(v.x, v.y), pk2(v.z, v.w)};
        *(uint2*)&d[t * 4] = o;
    } else {                                // prep: wc[] = rp_w2 @ {rp_b1, rp_w1} + rp_b2
        __shared__ float red[4][64][3];
        int d = tid & 63, p = tid >> 6;
        float w0 = 0.f, w1 = 0.f, cc = 0.f;
        #pragma unroll
        for (int jj = 0; jj < 16; jj++) {
            int j = p * 16 + jj;
            float r2 = rp_w2[d * 64 + j];
            w0 += r2 * rp_w1[j * 2 + 0];
            w1 += r2 * rp_w1[j * 2 + 1];
            cc += r2 * rp_b1[j];
        }
        red[p][d][0] = w0; red[p][d][1] = w1; red[p][d][2] = cc;
        __syncthreads();
        if (p == 0) {
            w0 = red[0][d][0] + red[1][d][0] + red[2][d][0] + red[3][d][0];
            w1 = red[0][d][1] + red[1][d][1] + red[2][d][1] + red[3][d][1];
            cc = red[0][d][2] + red[1][d][2] + red[2][d][2] + red[3][d][2];
            ws[d] = cc + rp_b2[d];
            ws[64 + 2 * d + 0] = w0;
            ws[64 + 2 * d + 1] = w1;
        }
    }
}

#define GP 72

// ---------------------------------------------------------------------------
// Merged Q/K/V projection GEMM. R6: epilogue now transposes the 64x64 output
// tile through LDS (25.6KB scratch, reusing the staging buffers) so global
// stores are contiguous 16B/lane runs. Previously MODE2 (Vt) issued 16 scalar
// ushort stores/thread at 2KB stride = 64 cache lines per 128B delivered —
// the suspected dominant cost of the non-attn pipeline (R5 post-mortem).
// Y[n,o] = sum_m X[n,m]*Wt[o,m]; N=4096, O=512, M=512; fp32 X read directly.
// ---------------------------------------------------------------------------
__global__ __launch_bounds__(256)
void mfma_gemm_qkv(const float* __restrict__ xq, const float* __restrict__ xk,
                   const float* __restrict__ xv,
                   const ushort_t* __restrict__ wq, const ushort_t* __restrict__ wk,
                   const ushort_t* __restrict__ wv,
                   ushort_t* __restrict__ Qbf, ushort_t* __restrict__ Kbf,
                   ushort_t* __restrict__ Vt, const float* __restrict__ wc)
{
    __shared__ ushort_t Sb[12800];          // 25.6 KB: staging (9216 used) / epilogue (12800)
    ushort_t* Xs = Sb;
    ushort_t* Ws = Sb + 64 * GP;
    const int bz = blockIdx.z;
    const float* X = (bz == 0) ? xq : (bz == 1) ? xk : xv;
    const ushort_t* Wt = (bz == 0) ? wq : (bz == 1) ? wk : wv;
    const int n0 = blockIdx.y * 64;
    const int o0 = blockIdx.x * 64;
    const int tid = threadIdx.x;
    const int wave = tid >> 6, lane = tid & 63;
    const int m16 = lane & 15, g = lane >> 4;

    f32x4 acc[4] = {};
    for (int m0 = 0; m0 < 512; m0 += 64) {
        #pragma unroll
        for (int it = 0; it < 2; it++) {
            int idx = tid + it * 256;
            int row = idx >> 3, c8 = (idx & 7) * 8;
            float4 a = *(const float4*)&X[(n0 + row) * 512 + m0 + c8];
            float4 b = *(const float4*)&X[(n0 + row) * 512 + m0 + c8 + 4];
            uint4 o = {pk2(a.x, a.y), pk2(a.z, a.w), pk2(b.x, b.y), pk2(b.z, b.w)};
            *(uint4*)&Xs[row * GP + c8] = o;
            *(uint4*)&Ws[row * GP + c8] = *(const uint4*)&Wt[(o0 + row) * 512 + m0 + c8];
        }
        __syncthreads();
        #pragma unroll
        for (int kc = 0; kc < 2; kc++) {
            bf16x8 a = *(const bf16x8*)&Xs[(wave * 16 + m16) * GP + kc * 32 + g * 8];
            #pragma unroll
            for (int to = 0; to < 4; to++) {
                bf16x8 b = *(const bf16x8*)&Ws[(to * 16 + m16) * GP + kc * 32 + g * 8];
                acc[to] = __builtin_amdgcn_mfma_f32_16x16x32_bf16(a, b, acc[to], 0, 0, 0);
            }
        }
        __syncthreads();                    // also protects Sb before epilogue reuse
    }

    const int b = n0 >> 10, s0 = n0 & 1023, h = o0 >> 6;
    const int bh = b * NHD + h;
    const int srow = wave * 16 + g * 4;     // local n (s) base for this thread

    if (bz == 0) {
        // T[s][d], pitch 72 (144B rows, 16B-aligned; write = 2-way alias, free)
        #pragma unroll
        for (int to = 0; to < 4; to++)
            #pragma unroll
            for (int r = 0; r < 4; r++)
                Sb[(srow + r) * GP + to * 16 + m16] = f2bf(acc[to][r]);
        __syncthreads();
        #pragma unroll
        for (int it = 0; it < 2; it++) {    // 512 chunks of 16B
            int cid = tid + it * 256;
            int row = cid >> 3, c8 = (cid & 7) * 8;
            *(uint4*)&Qbf[((bh << 10) + s0 + row) * 64 + c8] =
                *(const uint4*)&Sb[row * GP + c8];
        }
    } else if (bz == 1) {
        // T[s][seg*64+d], pitch 200 (400B rows, 16B-aligned)
        #pragma unroll
        for (int to = 0; to < 4; to++) {
            int d = to * 16 + m16;
            float c0 = wc[d], c1 = wc[64 + 2 * d], c2 = wc[64 + 2 * d + 1];
            #pragma unroll
            for (int r = 0; r < 4; r++) {
                float a = acc[to][r];
                int rb = (srow + r) * 200 + d;
                Sb[rb]       = f2bf(a * c0);
                Sb[rb + 64]  = f2bf(a * c1);
                Sb[rb + 128] = f2bf(a * c2);
            }
        }
        __syncthreads();
        #pragma unroll
        for (int it = 0; it < 6; it++) {    // 1536 chunks of 16B
            int cid = tid + it * 256;
            int row = cid / 24, c = cid % 24;
            *(uint4*)&Kbf[((bh << 10) + s0 + row) * 192 + c * 8] =
                *(const uint4*)&Sb[row * 200 + c * 8];
        }
    } else {
        // T[d][s], pitch 72
        #pragma unroll
        for (int to = 0; to < 4; to++)
            #pragma unroll
            for (int r = 0; r < 4; r++)
                Sb[(to * 16 + m16) * GP + srow + r] = f2bf(acc[to][r]);
        __syncthreads();
        #pragma unroll
        for (int it = 0; it < 2; it++) {    // 512 chunks of 16B
            int cid = tid + it * 256;
            int row = cid >> 3, c8 = (cid & 7) * 8;   // row = d, c8 = s offset
            *(uint4*)&Vt[(bh * 64 + row) * 1024 + s0 + c8] =
                *(const uint4*)&Sb[row * GP + c8];
        }
    }
}

// Output-projection GEMM (bf16 X, fp32 out + residual). N=4096, O=512, M=512.
__global__ __launch_bounds__(256)
void mfma_gemm_fc(const ushort_t* __restrict__ X, const ushort_t* __restrict__ Wt,
                  float* __restrict__ ofp, const float* __restrict__ resid)
{
    __shared__ ushort_t Xs[64 * GP];
    __shared__ ushort_t Ws[64 * GP];
    const int n0 = blockIdx.y * 64;
    const int o0 = blockIdx.x * 64;
    const int tid = threadIdx.x;
    const int wave = tid >> 6, lane = tid & 63;
    const int m16 = lane & 15, g = lane >> 4;

    f32x4 acc[4] = {};
    for (int m0 = 0; m0 < 512; m0 += 64) {
        #pragma unroll
        for (int it = 0; it < 2; it++) {
            int idx = tid + it * 256;
            int row = idx >> 3, c8 = (idx & 7) * 8;
            *(uint4*)&Xs[row * GP + c8] = *(const uint4*)&X[(n0 + row) * 512 + m0 + c8];
            *(uint4*)&Ws[row * GP + c8] = *(const uint4*)&Wt[(o0 + row) * 512 + m0 + c8];
        }
        __syncthreads();
        #pragma unroll
        for (int kc = 0; kc < 2; kc++) {
            bf16x8 a = *(const bf16x8*)&Xs[(wave * 16 + m16) * GP + kc * 32 + g * 8];
            #pragma unroll
            for (int to = 0; to < 4; to++) {
                bf16x8 b = *(const bf16x8*)&Ws[(to * 16 + m16) * GP + kc * 32 + g * 8];
                acc[to] = __builtin_amdgcn_mfma_f32_16x16x32_bf16(a, b, acc[to], 0, 0, 0);
            }
        }
        __syncthreads();
    }
    #pragma unroll
    for (int to = 0; to < 4; to++) {
        int o = o0 + to * 16 + m16;
        #pragma unroll
        for (int r = 0; r < 4; r++) {
            int n = n0 + wave * 16 + g * 4 + r;
            ofp[n * 512 + o] = acc[to][r] + resid[n * 512 + o];
        }
    }
}

// ---------------------------------------------------------------------------
// Fused score + softmax + PV — EXACT R3/R5 version (88 µs measured). Ledger:
//   R1: static-max softmax + __expf + Q-in-regs (exposed pos-load latency)
//   R3: pos packed bf16 + staged via LDS coalesced  -> 231 -> 89.4 µs
//   R4: reg-array prefetch -> compiler spill -> 201 µs (REVERTED)
//   R5: verbatim revert reproduced 88 µs. DO NOT TOUCH without A/B guard.
// ---------------------------------------------------------------------------
#define QPITCH 72
#define KPLANE (64 * QPITCH + 8)
#define POSP 68   // uints per pos row: 64 + 4 pad (row pitch 272B, 16B-aligned)
__global__ __launch_bounds__(256)
void fused_attn(const ushort_t* __restrict__ Qbf, const ushort_t* __restrict__ Kbf,
                const unsigned* __restrict__ posu, const ushort_t* __restrict__ Vt,
                float* __restrict__ attn, ushort_t* __restrict__ Obf)
{
    __shared__ ushort_t Ks[3 * KPLANE];      // 27696 B
    __shared__ ushort_t Vs[64 * QPITCH];     //  9216 B
    __shared__ ushort_t Ps[64 * QPITCH];     //  9216 B
    __shared__ unsigned PosS[64 * POSP];     // 17408 B   (total 63536 B)
    const int bh = blockIdx.x;
    const int q0 = blockIdx.y * 64;
    const int tid = threadIdx.x;
    const int wave = tid >> 6, lane = tid & 63;
    const int m16 = lane & 15, g = lane >> 4;

    // Q fragment directly global -> registers (one-time, 16B x2 per thread)
    const ushort_t* qrow = &Qbf[((bh << 10) + q0 + wave * 16 + m16) * 64];
    bf16x8 qf0 = *(const bf16x8*)&qrow[g * 8];
    bf16x8 qf1 = *(const bf16x8*)&qrow[32 + g * 8];

    float l[4] = {0.f, 0.f, 0.f, 0.f};

    // ---------------- pass 1: denominator sum (static max = 0) ----------------
    for (int k0 = 0; k0 < 1024; k0 += 64) {
        #pragma unroll
        for (int it = 0; it < 6; it++) {
            int idx = tid + it * 256;
            int row = idx / 24, c = idx % 24;
            int j = c >> 3, d8 = (c & 7) * 8;
            *(uint4*)&Ks[j * KPLANE + row * QPITCH + d8] =
                *(const uint4*)&Kbf[((bh << 10) + k0 + row) * 192 + c * 8];
        }
        #pragma unroll
        for (int it = 0; it < 4; it++) {
            int idx = tid + it * 256;              // 0..1023
            int row = idx >> 4, c4 = (idx & 15) * 4;
            *(uint4*)&PosS[row * POSP + c4] =
                *(const uint4*)&posu[(q0 + row) * 1024 + k0 + c4];
        }
        __syncthreads();

        f32x4 sc[4][3] = {};
        #pragma unroll
        for (int kc = 0; kc < 2; kc++) {
            bf16x8 af = kc ? qf1 : qf0;
            #pragma unroll
            for (int tk = 0; tk < 4; tk++)
                #pragma unroll
                for (int j = 0; j < 3; j++) {
                    bf16x8 bfv = *(const bf16x8*)&Ks[j * KPLANE + (tk * 16 + m16) * QPITCH + kc * 32 + g * 8];
                    sc[tk][j] = __builtin_amdgcn_mfma_f32_16x16x32_bf16(af, bfv, sc[tk][j], 0, 0, 0);
                }
        }

        #pragma unroll
        for (int r = 0; r < 4; r++) {
            #pragma unroll
            for (int tk = 0; tk < 4; tk++) {
                unsigned pu = PosS[(wave * 16 + g * 4 + r) * POSP + tk * 16 + m16];
                float p0 = __builtin_bit_cast(float, pu << 16);
                float p1 = __builtin_bit_cast(float, pu & 0xFFFF0000u);
                float s = (sc[tk][0][r] + p0 * sc[tk][1][r] + p1 * sc[tk][2][r]) * 0.125f;
                l[r] += __expf(s);
            }
        }
        __syncthreads();
    }
    // single cross-lane reduce (16-lane groups share the same q rows)
    float inv_l[4];
    #pragma unroll
    for (int r = 0; r < 4; r++) {
        float s = l[r];
        #pragma unroll
        for (int msk = 1; msk < 16; msk <<= 1) s += __shfl_xor(s, msk, 64);
        inv_l[r] = 1.0f / s;
    }

    // ---------------- pass 2: probs write + PV ----------------
    f32x4 ao[4] = {};
    for (int k0 = 0; k0 < 1024; k0 += 64) {
        #pragma unroll
        for (int it = 0; it < 6; it++) {
            int idx = tid + it * 256;
            int row = idx / 24, c = idx % 24;
            int j = c >> 3, d8 = (c & 7) * 8;
            *(uint4*)&Ks[j * KPLANE + row * QPITCH + d8] =
                *(const uint4*)&Kbf[((bh << 10) + k0 + row) * 192 + c * 8];
        }
        #pragma unroll
        for (int it = 0; it < 2; it++) {
            int idx = tid + it * 256;
            int row = idx >> 3, c8 = (idx & 7) * 8;
            *(uint4*)&Vs[row * QPITCH + c8] = *(const uint4*)&Vt[(bh * 64 + row) * 1024 + k0 + c8];
        }
        #pragma unroll
        for (int it = 0; it < 4; it++) {
            int idx = tid + it * 256;
            int row = idx >> 4, c4 = (idx & 15) * 4;
            *(uint4*)&PosS[row * POSP + c4] =
                *(const uint4*)&posu[(q0 + row) * 1024 + k0 + c4];
        }
        __syncthreads();

        f32x4 sc[4][3] = {};
        #pragma unroll
        for (int kc = 0; kc < 2; kc++) {
            bf16x8 af = kc ? qf1 : qf0;
            #pragma unroll
            for (int tk = 0; tk < 4; tk++)
                #pragma unroll
                for (int j = 0; j < 3; j++) {
                    bf16x8 bfv = *(const bf16x8*)&Ks[j * KPLANE + (tk * 16 + m16) * QPITCH + kc * 32 + g * 8];
                    sc[tk][j] = __builtin_amdgcn_mfma_f32_16x16x32_bf16(af, bfv, sc[tk][j], 0, 0, 0);
                }
        }

        #pragma unroll
        for (int r = 0; r < 4; r++) {
            int q = q0 + wave * 16 + g * 4 + r;
            #pragma unroll
            for (int tk = 0; tk < 4; tk++) {
                unsigned pu = PosS[(wave * 16 + g * 4 + r) * POSP + tk * 16 + m16];
                float p0 = __builtin_bit_cast(float, pu << 16);
                float p1 = __builtin_bit_cast(float, pu & 0xFFFF0000u);
                float s = (sc[tk][0][r] + p0 * sc[tk][1][r] + p1 * sc[tk][2][r]) * 0.125f;
                float p = __expf(s) * inv_l[r];
                attn[((bh << 10) + q) * 1024 + k0 + tk * 16 + m16] = p;
                Ps[(wave * 16 + g * 4 + r) * QPITCH + tk * 16 + m16] = f2bf(p);
            }
        }
        __syncthreads();

        #pragma unroll
        for (int kc = 0; kc < 2; kc++) {
            bf16x8 a = *(const bf16x8*)&Ps[(wave * 16 + m16) * QPITCH + kc * 32 + g * 8];
            #pragma unroll
            for (int td = 0; td < 4; td++) {
                bf16x8 b = *(const bf16x8*)&Vs[(td * 16 + m16) * QPITCH + kc * 32 + g * 8];
                ao[td] = __builtin_amdgcn_mfma_f32_16x16x32_bf16(a, b, ao[td], 0, 0, 0);
            }
        }
        __syncthreads();
    }

    const int b = bh >> 3, h = bh & 7;
    #pragma unroll
    for (int td = 0; td < 4; td++) {
        int d = td * 16 + m16;
        #pragma unroll
        for (int r = 0; r < 4; r++) {
            int q = q0 + wave * 16 + g * 4 + r;
            Obf[((b << 10) + q) * 512 + h * 64 + d] = f2bf(ao[td][r]);
        }
    }
}

__global__ __launch_bounds__(256)
void ln_kernel(const float* __restrict__ X, const float* __restrict__ g,
               const float* __restrict__ bta, float* __restrict__ out)
{
    const int row = blockIdx.x;
    const int tid = threadIdx.x;
    float2 x = *(const float2*)&X[row * 512 + tid * 2];
    float s  = x.x + x.y;
    float s2 = x.x * x.x + x.y * x.y;
    for (int off = 32; off; off >>= 1) {
        s  += __shfl_down(s, off, 64);
        s2 += __shfl_down(s2, off, 64);
    }
    __shared__ float rs[4], rs2[4];
    __shared__ float mu_s, rstd_s;
    int wave = tid >> 6, lane = tid & 63;
    if (lane == 0) { rs[wave] = s; rs2[wave] = s2; }
    __syncthreads();
    if (tid == 0) {
        float S1 = rs[0] + rs[1] + rs[2] + rs[3];
        float S2 = rs2[0] + rs2[1] + rs2[2] + rs2[3];
        float mu = S1 * (1.0f / 512.0f);
        float var = S2 * (1.0f / 512.0f) - mu * mu;
        mu_s = mu;
        rstd_s = rsqrtf(var + 1e-6f);
    }
    __syncthreads();
    float mu = mu_s, rstd = rstd_s;
    float2 gv = *(const float2*)&g[tid * 2];
    float2 bv = *(const float2*)&bta[tid * 2];
    float2 o;
    o.x = (x.x - mu) * rstd * gv.x + bv.x;
    o.y = (x.y - mu) * rstd * gv.y + bv.y;
    *(float2*)&out[row * 512 + tid * 2] = o;
}

extern "C" void kernel_launch(void* const* d_in, const int* in_sizes, int n_in,
                              void* d_out, int out_size, void* d_ws, size_t ws_size,
                              hipStream_t stream)
{
    const float* q       = (const float*)d_in[0];
    const float* k       = (const float*)d_in[1];
    const float* v       = (const float*)d_in[2];
    const float* pos_mat = (const float*)d_in[3];
    const float* w_qs    = (const float*)d_in[4];
    const float* w_ks    = (const float*)d_in[5];
    const float* w_vs    = (const float*)d_in[6];
    const float* w_fc    = (const float*)d_in[7];
    const float* rp_w1   = (const float*)d_in[8];
    const float* rp_b1   = (const float*)d_in[9];
    const float* rp_w2   = (const float*)d_in[10];
    const float* rp_b2   = (const float*)d_in[11];
    const float* ln_g    = (const float*)d_in[12];
    const float* ln_b    = (const float*)d_in[13];

    char* wsb = (char*)d_ws;
    float*    wc  = (float*)d_ws;
    ushort_t* WQ  = (ushort_t*)(wsb + WQ_OFF);
    ushort_t* WK  = (ushort_t*)(wsb + WK_OFF);
    ushort_t* WV  = (ushort_t*)(wsb + WV_OFF);
    ushort_t* WF  = (ushort_t*)(wsb + WF_OFF);
    ushort_t* Qbf = (ushort_t*)(wsb + QBF_OFF);
    ushort_t* Kbf = (ushort_t*)(wsb + KBF_OFF);
    ushort_t* Vt  = (ushort_t*)(wsb + VT_OFF);
    float*    O2  = (float*)(wsb + O2_OFF);
    ushort_t* Obf = (ushort_t*)(wsb + OBF_OFF);
    unsigned* Pbf = (unsigned*)(wsb + POSBF_OFF);

    float* out  = (float*)d_out;       // final (B,S,512)
    float* attn = out + 2097152;       // (B,H,S,S) probs

    setup_kernel<<<dim3(2049), 256, 0, stream>>>(pos_mat, w_qs, w_ks, w_vs, w_fc,
                                                 rp_w1, rp_b1, rp_w2, rp_b2,
                                                 Pbf, WQ, WK, WV, WF, wc);

    mfma_gemm_qkv<<<dim3(8, 64, 3), 256, 0, stream>>>(q, k, v, WQ, WK, WV,
                                                      Qbf, Kbf, Vt, wc);

    fused_attn<<<dim3(32, 16), 256, 0, stream>>>(Qbf, Kbf, Pbf, Vt, attn, Obf);

    mfma_gemm_fc<<<dim3(8, 64), 256, 0, stream>>>(Obf, WF, O2, q);
    ln_kernel<<<dim3(4096), 256, 0, stream>>>(O2, ln_g, ln_b, out);
}

// Round 8
// 281.608 us; speedup vs baseline: 1.0844x; 1.0844x over previous
//
#include <hip/hip_runtime.h>
#include <math.h>

// Problem constants
#define NB   4
#define SEQ  1024
#define DMOD 512
#define NHD  8
#define DK   64

typedef unsigned short ushort_t;
typedef __attribute__((ext_vector_type(8))) short bf16x8;
typedef __attribute__((ext_vector_type(4))) float f32x4;

// ---------------- workspace layout (bytes) ----------------
#define XQ_OFF   1024
#define XK_OFF   (XQ_OFF + 4194304)
#define XV_OFF   (XK_OFF + 4194304)
#define WQ_OFF   (XV_OFF + 4194304)
#define WK_OFF   (WQ_OFF + 524288)
#define WV_OFF   (WK_OFF + 524288)
#define WF_OFF   (WV_OFF + 524288)
#define QBF_OFF  (WF_OFF + 524288)
#define KBF_OFF  (QBF_OFF + 4194304)
#define VT_OFF   (KBF_OFF + 12582912)
// aliases (stream-ordered safe):
#define POSBF_OFF XQ_OFF  // 4MB packed-bf16 pos; written by setup, read by
                          // fused_attn, overwritten by O2 afterwards.
#define O2_OFF   XQ_OFF   // fp32 8MB, written by fc AFTER fused_attn
#define OBF_OFF  XV_OFF   // bf16 4MB, written by fused_attn

__device__ inline ushort_t f2bf(float x) {
    unsigned u = __builtin_bit_cast(unsigned, x);
    unsigned r = (u + 0x7FFFu + ((u >> 16) & 1u)) >> 16;
    return (ushort_t)r;
}
__device__ inline unsigned pk2(float a, float b) {
    return (unsigned)f2bf(a) | ((unsigned)f2bf(b) << 16);
}

// ---------------------------------------------------------------------------
// Merged setup kernel (R6, unchanged): poscvt (blocks 0..1023) + weight cvt
// (1024..2047) + parallelized prep (block 2048).
// ---------------------------------------------------------------------------
__global__ __launch_bounds__(256)
void setup_kernel(const float* __restrict__ pos,
                  const float* __restrict__ w_qs, const float* __restrict__ w_ks,
                  const float* __restrict__ w_vs, const float* __restrict__ w_fc,
                  const float* __restrict__ rp_w1, const float* __restrict__ rp_b1,
                  const float* __restrict__ rp_w2, const float* __restrict__ rp_b2,
                  unsigned* __restrict__ posbf,
                  ushort_t* __restrict__ WQ, ushort_t* __restrict__ WK,
                  ushort_t* __restrict__ WV, ushort_t* __restrict__ WF,
                  float* __restrict__ ws)
{
    const int bid = blockIdx.x;
    const int tid = threadIdx.x;
    if (bid < 1024) {                       // pos -> packed bf16 pairs
        int t = bid * 256 + tid;
        float4 a = *(const float4*)&pos[t * 8];
        float4 b = *(const float4*)&pos[t * 8 + 4];
        uint4 o = {pk2(a.x, a.y), pk2(a.z, a.w), pk2(b.x, b.y), pk2(b.z, b.w)};
        *(uint4*)&posbf[t * 4] = o;
    } else if (bid < 2048) {                // 4 weight matrices -> bf16
        int which = (bid - 1024) >> 8;
        int t = ((bid - 1024) & 255) * 256 + tid;
        const float* s = (which == 0) ? w_qs : (which == 1) ? w_ks
                       : (which == 2) ? w_vs : w_fc;
        ushort_t* d = (which == 0) ? WQ : (which == 1) ? WK
                    : (which == 2) ? WV : WF;
        float4 v = *(const float4*)&s[t * 4];
        uint2 o = {pk2(v.x, v.y), pk2(v.z, v.w)};
        *(uint2*)&d[t * 4] = o;
    } else {                                // prep: wc[] = rp_w2 @ {rp_b1, rp_w1} + rp_b2
        __shared__ float red[4][64][3];
        int d = tid & 63, p = tid >> 6;
        float w0 = 0.f, w1 = 0.f, cc = 0.f;
        #pragma unroll
        for (int jj = 0; jj < 16; jj++) {
            int j = p * 16 + jj;
            float r2 = rp_w2[d * 64 + j];
            w0 += r2 * rp_w1[j * 2 + 0];
            w1 += r2 * rp_w1[j * 2 + 1];
            cc += r2 * rp_b1[j];
        }
        red[p][d][0] = w0; red[p][d][1] = w1; red[p][d][2] = cc;
        __syncthreads();
        if (p == 0) {
            w0 = red[0][d][0] + red[1][d][0] + red[2][d][0] + red[3][d][0];
            w1 = red[0][d][1] + red[1][d][1] + red[2][d][1] + red[3][d][1];
            cc = red[0][d][2] + red[1][d][2] + red[2][d][2] + red[3][d][2];
            ws[d] = cc + rp_b2[d];
            ws[64 + 2 * d + 0] = w0;
            ws[64 + 2 * d + 1] = w1;
        }
    }
}

#define GP 72

// ---------------------------------------------------------------------------
// Q/K/V projection GEMM, R7 rebuild:
//  (a) n-major grid (64,8,3): wgid%8 = n-tile -> all 8 o-blocks sharing an X
//      n-tile land on ONE XCD; X slice fetched once per XCD instead of 8x
//      (same mechanism measured in fused_attn: FETCH 50MB = 24 ideal + pos*8).
//  (b) double-buffered LDS, one barrier/iter: next tile's global loads issued
//      into regs at loop top (latency hidden under MFMA), reg->LDS into the
//      other buffer after compute. Staging set = 24 VGPR on ~70 base (R4's
//      spill trap had 224B/thread on a 104 base — this is safe).
// Y[n,o] = sum_m X[n,m]*Wt[o,m]; N=4096, O=512, M=512; fp32 X read directly.
// ---------------------------------------------------------------------------
__global__ __launch_bounds__(256)
void mfma_gemm_qkv(const float* __restrict__ xq, const float* __restrict__ xk,
                   const float* __restrict__ xv,
                   const ushort_t* __restrict__ wq, const ushort_t* __restrict__ wk,
                   const ushort_t* __restrict__ wv,
                   ushort_t* __restrict__ Qbf, ushort_t* __restrict__ Kbf,
                   ushort_t* __restrict__ Vt, const float* __restrict__ wc)
{
    __shared__ ushort_t SH[18432];          // 36.9KB: {X0,X1,W0,W1} 4608 each; epilogue reuse
    const int bz = blockIdx.z;
    const float* X = (bz == 0) ? xq : (bz == 1) ? xk : xv;
    const ushort_t* Wt = (bz == 0) ? wq : (bz == 1) ? wk : wv;
    const int n0 = blockIdx.x * 64;         // n-major: XCD = blockIdx.x % 8
    const int o0 = blockIdx.y * 64;
    const int tid = threadIdx.x;
    const int wave = tid >> 6, lane = tid & 63;
    const int m16 = lane & 15, g = lane >> 4;
    const int sr = tid >> 3, sc8 = (tid & 7) * 8;   // staging row (0..31), col*8

    float4 xa0, xb0, xa1, xb1;              // staged X (fp32, cvt on store)
    uint4  wr0, wr1;                        // staged W (bf16)

#define LOADT(m0_) { \
    xa0 = *(const float4*)&X[(n0 + sr) * 512 + (m0_) + sc8]; \
    xb0 = *(const float4*)&X[(n0 + sr) * 512 + (m0_) + sc8 + 4]; \
    xa1 = *(const float4*)&X[(n0 + sr + 32) * 512 + (m0_) + sc8]; \
    xb1 = *(const float4*)&X[(n0 + sr + 32) * 512 + (m0_) + sc8 + 4]; \
    wr0 = *(const uint4*)&Wt[(o0 + sr) * 512 + (m0_) + sc8]; \
    wr1 = *(const uint4*)&Wt[(o0 + sr + 32) * 512 + (m0_) + sc8]; }
#define STORET(b_) { \
    ushort_t* Xs_ = SH + (b_) * 4608; \
    ushort_t* Ws_ = SH + 9216 + (b_) * 4608; \
    uint4 ox0 = {pk2(xa0.x, xa0.y), pk2(xa0.z, xa0.w), pk2(xb0.x, xb0.y), pk2(xb0.z, xb0.w)}; \
    uint4 ox1 = {pk2(xa1.x, xa1.y), pk2(xa1.z, xa1.w), pk2(xb1.x, xb1.y), pk2(xb1.z, xb1.w)}; \
    *(uint4*)&Xs_[sr * GP + sc8] = ox0; \
    *(uint4*)&Xs_[(sr + 32) * GP + sc8] = ox1; \
    *(uint4*)&Ws_[sr * GP + sc8] = wr0; \
    *(uint4*)&Ws_[(sr + 32) * GP + sc8] = wr1; }

    f32x4 acc[4] = {};
    LOADT(0); STORET(0);
    __syncthreads();
    int cur = 0;
    for (int m0 = 0; m0 < 512; m0 += 64) {
        const int nxt = m0 + 64;
        if (nxt < 512) LOADT(nxt);
        const ushort_t* Xs = SH + cur * 4608;
        const ushort_t* Ws = SH + 9216 + cur * 4608;
        #pragma unroll
        for (int kc = 0; kc < 2; kc++) {
            bf16x8 a = *(const bf16x8*)&Xs[(wave * 16 + m16) * GP + kc * 32 + g * 8];
            #pragma unroll
            for (int to = 0; to < 4; to++) {
                bf16x8 b = *(const bf16x8*)&Ws[(to * 16 + m16) * GP + kc * 32 + g * 8];
                acc[to] = __builtin_amdgcn_mfma_f32_16x16x32_bf16(a, b, acc[to], 0, 0, 0);
            }
        }
        if (nxt < 512) STORET(cur ^ 1);
        __syncthreads();
        cur ^= 1;
    }
#undef LOADT
#undef STORET

    const int b = n0 >> 10, s0 = n0 & 1023, h = o0 >> 6;
    const int bh = b * NHD + h;
    const int srow = wave * 16 + g * 4;

    if (bz == 0) {
        #pragma unroll
        for (int to = 0; to < 4; to++)
            #pragma unroll
            for (int r = 0; r < 4; r++)
                SH[(srow + r) * GP + to * 16 + m16] = f2bf(acc[to][r]);
        __syncthreads();
        #pragma unroll
        for (int it = 0; it < 2; it++) {
            int cid = tid + it * 256;
            int row = cid >> 3, c8 = (cid & 7) * 8;
            *(uint4*)&Qbf[((bh << 10) + s0 + row) * 64 + c8] =
                *(const uint4*)&SH[row * GP + c8];
        }
    } else if (bz == 1) {
        #pragma unroll
        for (int to = 0; to < 4; to++) {
            int d = to * 16 + m16;
            float c0 = wc[d], c1 = wc[64 + 2 * d], c2 = wc[64 + 2 * d + 1];
            #pragma unroll
            for (int r = 0; r < 4; r++) {
                float a = acc[to][r];
                int rb = (srow + r) * 200 + d;
                SH[rb]       = f2bf(a * c0);
                SH[rb + 64]  = f2bf(a * c1);
                SH[rb + 128] = f2bf(a * c2);
            }
        }
        __syncthreads();
        #pragma unroll
        for (int it = 0; it < 6; it++) {
            int cid = tid + it * 256;
            int row = cid / 24, c = cid % 24;
            *(uint4*)&Kbf[((bh << 10) + s0 + row) * 192 + c * 8] =
                *(const uint4*)&SH[row * 200 + c * 8];
        }
    } else {
        #pragma unroll
        for (int to = 0; to < 4; to++)
            #pragma unroll
            for (int r = 0; r < 4; r++)
                SH[(to * 16 + m16) * GP + srow + r] = f2bf(acc[to][r]);
        __syncthreads();
        #pragma unroll
        for (int it = 0; it < 2; it++) {
            int cid = tid + it * 256;
            int row = cid >> 3, c8 = (cid & 7) * 8;
            *(uint4*)&Vt[(bh * 64 + row) * 1024 + s0 + c8] =
                *(const uint4*)&SH[row * GP + c8];
        }
    }
}

// ---------------------------------------------------------------------------
// Output-projection GEMM, R7: same n-major grid + dbuf 2-phase as qkv.
// bf16 X (Obf), fp32 out + residual. N=4096, O=512, M=512.
// ---------------------------------------------------------------------------
__global__ __launch_bounds__(256)
void mfma_gemm_fc(const ushort_t* __restrict__ X, const ushort_t* __restrict__ Wt,
                  float* __restrict__ ofp, const float* __restrict__ resid)
{
    __shared__ ushort_t SH[18432];
    const int n0 = blockIdx.x * 64;         // n-major
    const int o0 = blockIdx.y * 64;
    const int tid = threadIdx.x;
    const int wave = tid >> 6, lane = tid & 63;
    const int m16 = lane & 15, g = lane >> 4;
    const int sr = tid >> 3, sc8 = (tid & 7) * 8;

    uint4 xr0, xr1, wr0, wr1;

#define LOADF(m0_) { \
    xr0 = *(const uint4*)&X[(n0 + sr) * 512 + (m0_) + sc8]; \
    xr1 = *(const uint4*)&X[(n0 + sr + 32) * 512 + (m0_) + sc8]; \
    wr0 = *(const uint4*)&Wt[(o0 + sr) * 512 + (m0_) + sc8]; \
    wr1 = *(const uint4*)&Wt[(o0 + sr + 32) * 512 + (m0_) + sc8]; }
#define STOREF(b_) { \
    ushort_t* Xs_ = SH + (b_) * 4608; \
    ushort_t* Ws_ = SH + 9216 + (b_) * 4608; \
    *(uint4*)&Xs_[sr * GP + sc8] = xr0; \
    *(uint4*)&Xs_[(sr + 32) * GP + sc8] = xr1; \
    *(uint4*)&Ws_[sr * GP + sc8] = wr0; \
    *(uint4*)&Ws_[(sr + 32) * GP + sc8] = wr1; }

    f32x4 acc[4] = {};
    LOADF(0); STOREF(0);
    __syncthreads();
    int cur = 0;
    for (int m0 = 0; m0 < 512; m0 += 64) {
        const int nxt = m0 + 64;
        if (nxt < 512) LOADF(nxt);
        const ushort_t* Xs = SH + cur * 4608;
        const ushort_t* Ws = SH + 9216 + cur * 4608;
        #pragma unroll
        for (int kc = 0; kc < 2; kc++) {
            bf16x8 a = *(const bf16x8*)&Xs[(wave * 16 + m16) * GP + kc * 32 + g * 8];
            #pragma unroll
            for (int to = 0; to < 4; to++) {
                bf16x8 b = *(const bf16x8*)&Ws[(to * 16 + m16) * GP + kc * 32 + g * 8];
                acc[to] = __builtin_amdgcn_mfma_f32_16x16x32_bf16(a, b, acc[to], 0, 0, 0);
            }
        }
        if (nxt < 512) STOREF(cur ^ 1);
        __syncthreads();
        cur ^= 1;
    }
#undef LOADF
#undef STOREF

    #pragma unroll
    for (int to = 0; to < 4; to++) {
        int o = o0 + to * 16 + m16;
        #pragma unroll
        for (int r = 0; r < 4; r++) {
            int n = n0 + wave * 16 + g * 4 + r;
            ofp[n * 512 + o] = acc[to][r] + resid[n * 512 + o];
        }
    }
}

// ---------------------------------------------------------------------------
// Fused score + softmax + PV — EXACT R3/R5 version (86-88 µs measured). Ledger:
//   R1: static-max softmax + __expf + Q-in-regs (exposed pos-load latency)
//   R3: pos packed bf16 + staged via LDS coalesced  -> 231 -> 89.4 µs
//   R4: reg-array prefetch -> compiler spill -> 201 µs (REVERTED)
//   R5/R6: frozen, reproduces 86-88 µs. DO NOT TOUCH without A/B guard.
// ---------------------------------------------------------------------------
#define QPITCH 72
#define KPLANE (64 * QPITCH + 8)
#define POSP 68   // uints per pos row: 64 + 4 pad (row pitch 272B, 16B-aligned)
__global__ __launch_bounds__(256)
void fused_attn(const ushort_t* __restrict__ Qbf, const ushort_t* __restrict__ Kbf,
                const unsigned* __restrict__ posu, const ushort_t* __restrict__ Vt,
                float* __restrict__ attn, ushort_t* __restrict__ Obf)
{
    __shared__ ushort_t Ks[3 * KPLANE];      // 27696 B
    __shared__ ushort_t Vs[64 * QPITCH];     //  9216 B
    __shared__ ushort_t Ps[64 * QPITCH];     //  9216 B
    __shared__ unsigned PosS[64 * POSP];     // 17408 B   (total 63536 B)
    const int bh = blockIdx.x;
    const int q0 = blockIdx.y * 64;
    const int tid = threadIdx.x;
    const int wave = tid >> 6, lane = tid & 63;
    const int m16 = lane & 15, g = lane >> 4;

    // Q fragment directly global -> registers (one-time, 16B x2 per thread)
    const ushort_t* qrow = &Qbf[((bh << 10) + q0 + wave * 16 + m16) * 64];
    bf16x8 qf0 = *(const bf16x8*)&qrow[g * 8];
    bf16x8 qf1 = *(const bf16x8*)&qrow[32 + g * 8];

    float l[4] = {0.f, 0.f, 0.f, 0.f};

    // ---------------- pass 1: denominator sum (static max = 0) ----------------
    for (int k0 = 0; k0 < 1024; k0 += 64) {
        #pragma unroll
        for (int it = 0; it < 6; it++) {
            int idx = tid + it * 256;
            int row = idx / 24, c = idx % 24;
            int j = c >> 3, d8 = (c & 7) * 8;
            *(uint4*)&Ks[j * KPLANE + row * QPITCH + d8] =
                *(const uint4*)&Kbf[((bh << 10) + k0 + row) * 192 + c * 8];
        }
        #pragma unroll
        for (int it = 0; it < 4; it++) {
            int idx = tid + it * 256;              // 0..1023
            int row = idx >> 4, c4 = (idx & 15) * 4;
            *(uint4*)&PosS[row * POSP + c4] =
                *(const uint4*)&posu[(q0 + row) * 1024 + k0 + c4];
        }
        __syncthreads();

        f32x4 sc[4][3] = {};
        #pragma unroll
        for (int kc = 0; kc < 2; kc++) {
            bf16x8 af = kc ? qf1 : qf0;
            #pragma unroll
            for (int tk = 0; tk < 4; tk++)
                #pragma unroll
                for (int j = 0; j < 3; j++) {
                    bf16x8 bfv = *(const bf16x8*)&Ks[j * KPLANE + (tk * 16 + m16) * QPITCH + kc * 32 + g * 8];
                    sc[tk][j] = __builtin_amdgcn_mfma_f32_16x16x32_bf16(af, bfv, sc[tk][j], 0, 0, 0);
                }
        }

        #pragma unroll
        for (int r = 0; r < 4; r++) {
            #pragma unroll
            for (int tk = 0; tk < 4; tk++) {
                unsigned pu = PosS[(wave * 16 + g * 4 + r) * POSP + tk * 16 + m16];
                float p0 = __builtin_bit_cast(float, pu << 16);
                float p1 = __builtin_bit_cast(float, pu & 0xFFFF0000u);
                float s = (sc[tk][0][r] + p0 * sc[tk][1][r] + p1 * sc[tk][2][r]) * 0.125f;
                l[r] += __expf(s);
            }
        }
        __syncthreads();
    }
    // single cross-lane reduce (16-lane groups share the same q rows)
    float inv_l[4];
    #pragma unroll
    for (int r = 0; r < 4; r++) {
        float s = l[r];
        #pragma unroll
        for (int msk = 1; msk < 16; msk <<= 1) s += __shfl_xor(s, msk, 64);
        inv_l[r] = 1.0f / s;
    }

    // ---------------- pass 2: probs write + PV ----------------
    f32x4 ao[4] = {};
    for (int k0 = 0; k0 < 1024; k0 += 64) {
        #pragma unroll
        for (int it = 0; it < 6; it++) {
            int idx = tid + it * 256;
            int row = idx / 24, c = idx % 24;
            int j = c >> 3, d8 = (c & 7) * 8;
            *(uint4*)&Ks[j * KPLANE + row * QPITCH + d8] =
                *(const uint4*)&Kbf[((bh << 10) + k0 + row) * 192 + c * 8];
        }
        #pragma unroll
        for (int it = 0; it < 2; it++) {
            int idx = tid + it * 256;
            int row = idx >> 3, c8 = (idx & 7) * 8;
            *(uint4*)&Vs[row * QPITCH + c8] = *(const uint4*)&Vt[(bh * 64 + row) * 1024 + k0 + c8];
        }
        #pragma unroll
        for (int it = 0; it < 4; it++) {
            int idx = tid + it * 256;
            int row = idx >> 4, c4 = (idx & 15) * 4;
            *(uint4*)&PosS[row * POSP + c4] =
                *(const uint4*)&posu[(q0 + row) * 1024 + k0 + c4];
        }
        __syncthreads();

        f32x4 sc[4][3] = {};
        #pragma unroll
        for (int kc = 0; kc < 2; kc++) {
            bf16x8 af = kc ? qf1 : qf0;
            #pragma unroll
            for (int tk = 0; tk < 4; tk++)
                #pragma unroll
                for (int j = 0; j < 3; j++) {
                    bf16x8 bfv = *(const bf16x8*)&Ks[j * KPLANE + (tk * 16 + m16) * QPITCH + kc * 32 + g * 8];
                    sc[tk][j] = __builtin_amdgcn_mfma_f32_16x16x32_bf16(af, bfv, sc[tk][j], 0, 0, 0);
                }
        }

        #pragma unroll
        for (int r = 0; r < 4; r++) {
            int q = q0 + wave * 16 + g * 4 + r;
            #pragma unroll
            for (int tk = 0; tk < 4; tk++) {
                unsigned pu = PosS[(wave * 16 + g * 4 + r) * POSP + tk * 16 + m16];
                float p0 = __builtin_bit_cast(float, pu << 16);
                float p1 = __builtin_bit_cast(float, pu & 0xFFFF0000u);
                float s = (sc[tk][0][r] + p0 * sc[tk][1][r] + p1 * sc[tk][2][r]) * 0.125f;
                float p = __expf(s) * inv_l[r];
                attn[((bh << 10) + q) * 1024 + k0 + tk * 16 + m16] = p;
                Ps[(wave * 16 + g * 4 + r) * QPITCH + tk * 16 + m16] = f2bf(p);
            }
        }
        __syncthreads();

        #pragma unroll
        for (int kc = 0; kc < 2; kc++) {
            bf16x8 a = *(const bf16x8*)&Ps[(wave * 16 + m16) * QPITCH + kc * 32 + g * 8];
            #pragma unroll
            for (int td = 0; td < 4; td++) {
                bf16x8 b = *(const bf16x8*)&Vs[(td * 16 + m16) * QPITCH + kc * 32 + g * 8];
                ao[td] = __builtin_amdgcn_mfma_f32_16x16x32_bf16(a, b, ao[td], 0, 0, 0);
            }
        }
        __syncthreads();
    }

    const int b = bh >> 3, h = bh & 7;
    #pragma unroll
    for (int td = 0; td < 4; td++) {
        int d = td * 16 + m16;
        #pragma unroll
        for (int r = 0; r < 4; r++) {
            int q = q0 + wave * 16 + g * 4 + r;
            Obf[((b << 10) + q) * 512 + h * 64 + d] = f2bf(ao[td][r]);
        }
    }
}

__global__ __launch_bounds__(256)
void ln_kernel(const float* __restrict__ X, const float* __restrict__ g,
               const float* __restrict__ bta, float* __restrict__ out)
{
    const int row = blockIdx.x;
    const int tid = threadIdx.x;
    float2 x = *(const float2*)&X[row * 512 + tid * 2];
    float s  = x.x + x.y;
    float s2 = x.x * x.x + x.y * x.y;
    for (int off = 32; off; off >>= 1) {
        s  += __shfl_down(s, off, 64);
        s2 += __shfl_down(s2, off, 64);
    }
    __shared__ float rs[4], rs2[4];
    __shared__ float mu_s, rstd_s;
    int wave = tid >> 6, lane = tid & 63;
    if (lane == 0) { rs[wave] = s; rs2[wave] = s2; }
    __syncthreads();
    if (tid == 0) {
        float S1 = rs[0] + rs[1] + rs[2] + rs[3];
        float S2 = rs2[0] + rs2[1] + rs2[2] + rs2[3];
        float mu = S1 * (1.0f / 512.0f);
        float var = S2 * (1.0f / 512.0f) - mu * mu;
        mu_s = mu;
        rstd_s = rsqrtf(var + 1e-6f);
    }
    __syncthreads();
    float mu = mu_s, rstd = rstd_s;
    float2 gv = *(const float2*)&g[tid * 2];
    float2 bv = *(const float2*)&bta[tid * 2];
    float2 o;
    o.x = (x.x - mu) * rstd * gv.x + bv.x;
    o.y = (x.y - mu) * rstd * gv.y + bv.y;
    *(float2*)&out[row * 512 + tid * 2] = o;
}

extern "C" void kernel_launch(void* const* d_in, const int* in_sizes, int n_in,
                              void* d_out, int out_size, void* d_ws, size_t ws_size,
                              hipStream_t stream)
{
    const float* q       = (const float*)d_in[0];
    const float* k       = (const float*)d_in[1];
    const float* v       = (const float*)d_in[2];
    const float* pos_mat = (const float*)d_in[3];
    const float* w_qs    = (const float*)d_in[4];
    const float* w_ks    = (const float*)d_in[5];
    const float* w_vs    = (const float*)d_in[6];
    const float* w_fc    = (const float*)d_in[7];
    const float* rp_w1   = (const float*)d_in[8];
    const float* rp_b1   = (const float*)d_in[9];
    const float* rp_w2   = (const float*)d_in[10];
    const float* rp_b2   = (const float*)d_in[11];
    const float* ln_g    = (const float*)d_in[12];
    const float* ln_b    = (const float*)d_in[13];

    char* wsb = (char*)d_ws;
    float*    wc  = (float*)d_ws;
    ushort_t* WQ  = (ushort_t*)(wsb + WQ_OFF);
    ushort_t* WK  = (ushort_t*)(wsb + WK_OFF);
    ushort_t* WV  = (ushort_t*)(wsb + WV_OFF);
    ushort_t* WF  = (ushort_t*)(wsb + WF_OFF);
    ushort_t* Qbf = (ushort_t*)(wsb + QBF_OFF);
    ushort_t* Kbf = (ushort_t*)(wsb + KBF_OFF);
    ushort_t* Vt  = (ushort_t*)(wsb + VT_OFF);
    float*    O2  = (float*)(wsb + O2_OFF);
    ushort_t* Obf = (ushort_t*)(wsb + OBF_OFF);
    unsigned* Pbf = (unsigned*)(wsb + POSBF_OFF);

    float* out  = (float*)d_out;       // final (B,S,512)
    float* attn = out + 2097152;       // (B,H,S,S) probs

    setup_kernel<<<dim3(2049), 256, 0, stream>>>(pos_mat, w_qs, w_ks, w_vs, w_fc,
                                                 rp_w1, rp_b1, rp_w2, rp_b2,
                                                 Pbf, WQ, WK, WV, WF, wc);

    // n-major grid: all o-blocks of an n-tile share an XCD (X slice 1 fetch/XCD)
    mfma_gemm_qkv<<<dim3(64, 8, 3), 256, 0, stream>>>(q, k, v, WQ, WK, WV,
                                                      Qbf, Kbf, Vt, wc);

    fused_attn<<<dim3(32, 16), 256, 0, stream>>>(Qbf, Kbf, Pbf, Vt, attn, Obf);

    mfma_gemm_fc<<<dim3(64, 8), 256, 0, stream>>>(Obf, WF, O2, q);
    ln_kernel<<<dim3(4096), 256, 0, stream>>>(O2, ln_g, ln_b, out);
}